// Round 1
// baseline (660.438 us; speedup 1.0000x reference)
//
#include <hip/hip_runtime.h>

#define B_TOTAL 262144
#define D_INN   200
#define HDIM    100
#define KH      64
#define BLK     128
#define LDS_STRIDE 101   // 101 mod 32 = 5, coprime -> conflict-free per-thread rows

__global__ __launch_bounds__(BLK)
void ar_gas_fused(const float* __restrict__ x,
                  const float* __restrict__ last_mu,
                  const float* __restrict__ last_sigma,
                  const float* __restrict__ p_amu,
                  const float* __restrict__ p_as,
                  const float* __restrict__ p_bmu,
                  const float* __restrict__ p_bs,
                  const float* __restrict__ p_omu,
                  const float* __restrict__ p_os,
                  const float* __restrict__ p_nu,
                  const float* __restrict__ p_ns,
                  const float* __restrict__ W1,
                  const float* __restrict__ b1,
                  const float* __restrict__ W2,
                  const float* __restrict__ b2,
                  const float* __restrict__ W3,
                  const float* __restrict__ b3,
                  float* __restrict__ out)
{
    __shared__ float lds_h[BLK * LDS_STRIDE];   // 50.5 KiB
    const int tid = threadIdx.x;
    const int b   = blockIdx.x * BLK + tid;
    if (b >= B_TOTAL) return;

    float* hrow = &lds_h[tid * LDS_STRIDE];

    // ---------- layer 1: h1 = relu(x @ W1 + b1) ----------
    float acc[HDIM];
    #pragma unroll
    for (int j = 0; j < HDIM; ++j) acc[j] = b1[j];

    const float* xrow = x + (size_t)b * D_INN;
    #pragma unroll 1
    for (int i = 0; i < D_INN; i += 4) {
        const float4 xv = *reinterpret_cast<const float4*>(xrow + i);
        const float* w = W1 + i * HDIM;           // uniform address -> s_load
        #pragma unroll
        for (int j = 0; j < HDIM; ++j) {
            float a = acc[j];
            a = fmaf(xv.x, w[j            ], a);
            a = fmaf(xv.y, w[j +     HDIM ], a);
            a = fmaf(xv.z, w[j + 2 * HDIM ], a);
            a = fmaf(xv.w, w[j + 3 * HDIM ], a);
            acc[j] = a;
        }
    }
    #pragma unroll
    for (int j = 0; j < HDIM; ++j) hrow[j] = fmaxf(acc[j], 0.0f);

    // ---------- layer 2: h2 = relu(h1 @ W2 + b2) ----------
    #pragma unroll
    for (int j = 0; j < HDIM; ++j) acc[j] = b2[j];
    #pragma unroll 1
    for (int i = 0; i < HDIM; ++i) {
        const float hv = hrow[i];                 // ds_read_b32, conflict-free
        const float* w = W2 + i * HDIM;
        #pragma unroll
        for (int j = 0; j < HDIM; ++j) acc[j] = fmaf(hv, w[j], acc[j]);
    }
    #pragma unroll
    for (int j = 0; j < HDIM; ++j) hrow[j] = fmaxf(acc[j], 0.0f);

    // ---------- layer 3: dp = h2 @ W3 + b3 ----------
    float dp[KH];
    #pragma unroll
    for (int j = 0; j < KH; ++j) dp[j] = b3[j];
    #pragma unroll 1
    for (int i = 0; i < HDIM; ++i) {
        const float hv = hrow[i];
        const float* w = W3 + i * KH;
        #pragma unroll
        for (int j = 0; j < KH; ++j) dp[j] = fmaf(hv, w[j], dp[j]);
    }

    // ---------- Student-t GAS recurrence (sequential over K) ----------
    const float a_mu = *p_amu, a_s = *p_as;
    const float b_mu = *p_bmu, b_s = *p_bs;
    const float o_mu = *p_omu, o_s = *p_os;
    const float nu   = *p_nu,  ns  = *p_ns;
    const float w_   = 1.0f + 1.0f / nu;

    float mu = last_mu[b];
    float s2 = last_sigma[b];   // variance state (strictly positive)
    #pragma unroll
    for (int k = 0; k < KH; ++k) {
        const float y  = dp[k];
        const float e  = y - mu;
        const float q  = (e * e) / (nu * s2);
        const float rd = 1.0f / (1.0f + q);
        const float mu_n = o_mu + ns * a_mu * (w_ * e * rd) + b_mu * mu;
        const float s2_n = o_s  + ns * a_s  * (w_ * e * e * rd - s2) + b_s * s2;
        mu = mu_n;
        s2 = s2_n;                       // s2 stays > 0 (omega>0, shrinkage)
        dp[k] = y * sqrtf(s2) + mu;      // deep_preds * sigma + mu
    }

    // ---------- coalesced-per-row store ----------
    float* orow = out + (size_t)b * KH;
    #pragma unroll
    for (int q4 = 0; q4 < KH; q4 += 4) {
        *reinterpret_cast<float4*>(orow + q4) =
            make_float4(dp[q4], dp[q4 + 1], dp[q4 + 2], dp[q4 + 3]);
    }
}

extern "C" void kernel_launch(void* const* d_in, const int* in_sizes, int n_in,
                              void* d_out, int out_size, void* d_ws, size_t ws_size,
                              hipStream_t stream) {
    const float* x          = (const float*)d_in[0];
    const float* last_mu    = (const float*)d_in[1];
    const float* last_sigma = (const float*)d_in[2];
    const float* amu        = (const float*)d_in[3];
    const float* asig       = (const float*)d_in[4];
    const float* bmu        = (const float*)d_in[5];
    const float* bsig       = (const float*)d_in[6];
    const float* omu        = (const float*)d_in[7];
    const float* osig       = (const float*)d_in[8];
    const float* nu         = (const float*)d_in[9];
    const float* ns         = (const float*)d_in[10];
    const float* W1         = (const float*)d_in[11];
    const float* b1         = (const float*)d_in[12];
    const float* W2         = (const float*)d_in[13];
    const float* b2         = (const float*)d_in[14];
    const float* W3         = (const float*)d_in[15];
    const float* b3         = (const float*)d_in[16];
    float* out = (float*)d_out;

    const int B = in_sizes[1];            // 262144 rows
    dim3 grid((B + BLK - 1) / BLK), block(BLK);
    hipLaunchKernelGGL(ar_gas_fused, grid, block, 0, stream,
                       x, last_mu, last_sigma,
                       amu, asig, bmu, bsig, omu, osig, nu, ns,
                       W1, b1, W2, b2, W3, b3, out);
}

// Round 2
// 107.913 us; speedup vs baseline: 6.1201x; 6.1201x over previous
//
#include <hip/hip_runtime.h>

typedef short v8s __attribute__((ext_vector_type(8)));
typedef float v4f __attribute__((ext_vector_type(4)));

#define THREADS 256
#define BMROWS  128
// uint4-index bases of the fragment-ready weight tables in d_ws
#define W1F_U4  0       // 49 frags * 64 uint4
#define W2F_U4  3136    // 28 frags
#define W3F_U4  4928    // 16 frags

__device__ __forceinline__ unsigned short f2bf(float f) {
    unsigned int u = __float_as_uint(f);
    return (unsigned short)((u + (((u >> 16) & 1u) + 0x7FFFu)) >> 16);  // RNE
}
__device__ __forceinline__ unsigned int pk2(float a, float b) {
    return (unsigned int)f2bf(a) | ((unsigned int)f2bf(b) << 16);
}
__device__ __forceinline__ v4f mfma16(v8s a, v8s b, v4f c) {
    return __builtin_amdgcn_mfma_f32_16x16x32_bf16(a, b, c, 0, 0, 0);
}

// ---- prep: weights -> MFMA B-fragment layout (bf16, zero-padded) ----------
// frag(nt,kc): lane l holds B[k = kc*32+(l>>4)*8+j][n = nt*16+(l&15)], j=0..7
__global__ void prep_weights(const float* __restrict__ W1,
                             const float* __restrict__ W2,
                             const float* __restrict__ W3,
                             uint4* __restrict__ wf) {
    const int bid = blockIdx.x, l = threadIdx.x;
    const float* W; int K, N, KC, base, f;
    if (bid < 49)      { W = W1; K = 200; N = 100; KC = 7; base = W1F_U4; f = bid; }
    else if (bid < 77) { W = W2; K = 100; N = 100; KC = 4; base = W2F_U4; f = bid - 49; }
    else               { W = W3; K = 100; N = 64;  KC = 4; base = W3F_U4; f = bid - 77; }
    const int kc = f % KC;
    const int n  = (f / KC) * 16 + (l & 15);
    unsigned int u[4];
    #pragma unroll
    for (int p = 0; p < 4; ++p) {
        const int k0 = kc * 32 + (l >> 4) * 8 + p * 2;
        const float a = (k0     < K && n < N) ? W[(size_t)k0 * N + n]       : 0.f;
        const float b = (k0 + 1 < K && n < N) ? W[(size_t)(k0 + 1) * N + n] : 0.f;
        u[p] = pk2(a, b);
    }
    wf[base + f * 64 + l] = make_uint4(u[0], u[1], u[2], u[3]);
}

// ---- LDS address helpers (XOR granule swizzle, all bank-balanced) ---------
// region A [0,32768): h1 bf16 [128][128], then DP f32 [128][64]
// region B [32768,65536): X dbuf 2x[128 rows][32 bf16], then h2 bf16 [128][128]
#define HADDR(base, row, g)  ((base) + (row) * 256 + ((((g) ^ ((row) & 7)) & 15) << 4))
#define XADDR(base, row, g)  ((base) + (row) * 64  + ((((g) ^ ((row) & 3)) & 3)  << 4))
#define DPADDR(row, q)       ((row) * 256 + ((((q) ^ ((row) & 15)) & 15) << 4))

__global__ __launch_bounds__(THREADS, 2)
void ar_gas_mfma(const float* __restrict__ x,
                 const float* __restrict__ last_mu,
                 const float* __restrict__ last_sigma,
                 const float* __restrict__ p_amu, const float* __restrict__ p_as,
                 const float* __restrict__ p_bmu, const float* __restrict__ p_bs,
                 const float* __restrict__ p_omu, const float* __restrict__ p_os,
                 const float* __restrict__ p_nu,  const float* __restrict__ p_ns,
                 const float* __restrict__ b1, const float* __restrict__ b2,
                 const float* __restrict__ b3,
                 const uint4* __restrict__ wf,
                 float* __restrict__ out)
{
    __shared__ __align__(16) unsigned char L[65536];
    const int tid  = threadIdx.x;
    const int lane = tid & 63;
    const int wid  = tid >> 6;
    const int l15  = lane & 15;
    const int l4   = lane >> 4;
    const int blk  = blockIdx.x;
    const size_t rowg0 = (size_t)blk * BMROWS;
    const int HB = 32768;

    // ================= layer 1: h1 = relu(X @ W1 + b1) =================
    v4f acc[2][7];
    #pragma unroll
    for (int mt = 0; mt < 2; ++mt)
        #pragma unroll
        for (int nt = 0; nt < 7; ++nt) acc[mt][nt] = (v4f){0.f, 0.f, 0.f, 0.f};

    float bv[7];
    #pragma unroll
    for (int nt = 0; nt < 7; ++nt) {
        const int c = nt * 16 + l15;
        bv[nt] = (c < 100) ? b1[c] : 0.f;
    }

    // prologue: stage chunk 0 into buf0 (f32 -> bf16)
    {
        #pragma unroll
        for (int i = 0; i < 4; ++i) {
            const int fi = tid + THREADS * i;
            const int row = fi >> 3, c4 = fi & 7;
            const int k0 = c4 * 4;
            float4 v = (k0 < 200) ? *(const float4*)(x + (rowg0 + row) * 200 + k0)
                                  : make_float4(0.f, 0.f, 0.f, 0.f);
            *(uint2*)(&L[XADDR(HB, row, c4 >> 1) + (c4 & 1) * 8]) =
                make_uint2(pk2(v.x, v.y), pk2(v.z, v.w));
        }
    }
    __syncthreads();

    #pragma unroll
    for (int kc = 0; kc < 7; ++kc) {
        const int cur = kc & 1;
        // T14: issue next chunk's global loads BEFORE compute
        float4 ld[4];
        if (kc < 6) {
            #pragma unroll
            for (int i = 0; i < 4; ++i) {
                const int fi = tid + THREADS * i;
                const int row = fi >> 3, c4 = fi & 7;
                const int k0 = (kc + 1) * 32 + c4 * 4;
                ld[i] = (k0 < 200) ? *(const float4*)(x + (rowg0 + row) * 200 + k0)
                                   : make_float4(0.f, 0.f, 0.f, 0.f);
            }
        }
        // A-frags from current chunk
        v8s af[2];
        #pragma unroll
        for (int mt = 0; mt < 2; ++mt) {
            const int row = wid * 32 + mt * 16 + l15;
            uint4 t = *(const uint4*)(&L[XADDR(HB + cur * 8192, row, l4)]);
            af[mt] = *(v8s*)&t;
        }
        #pragma unroll
        for (int nt = 0; nt < 7; ++nt) {
            uint4 bu = wf[W1F_U4 + (nt * 7 + kc) * 64 + lane];
            v8s bf = *(v8s*)&bu;
            acc[0][nt] = mfma16(af[0], bf, acc[0][nt]);
            acc[1][nt] = mfma16(af[1], bf, acc[1][nt]);
        }
        // write next chunk late (vmcnt wait folds here)
        if (kc < 6) {
            #pragma unroll
            for (int i = 0; i < 4; ++i) {
                const int fi = tid + THREADS * i;
                const int row = fi >> 3, c4 = fi & 7;
                *(uint2*)(&L[XADDR(HB + (cur ^ 1) * 8192, row, c4 >> 1) + (c4 & 1) * 8]) =
                    make_uint2(pk2(ld[i].x, ld[i].y), pk2(ld[i].z, ld[i].w));
            }
        }
        __syncthreads();
    }

    // epilogue -> h1 (region A), relu + bias, then zero-pad cols 112..127
    #pragma unroll
    for (int mt = 0; mt < 2; ++mt)
        #pragma unroll
        for (int nt = 0; nt < 7; ++nt) {
            v4f a = acc[mt][nt];
            #pragma unroll
            for (int r = 0; r < 4; ++r) {
                const int row = wid * 32 + mt * 16 + l4 * 4 + r;
                const int c   = nt * 16 + l15;
                const float v = fmaxf(a[r] + bv[nt], 0.f);
                *(unsigned short*)(&L[HADDR(0, row, c >> 3) + (c & 7) * 2]) = f2bf(v);
            }
        }
    {
        const int row = tid >> 1, g0 = 14 + (tid & 1);
        *(uint4*)(&L[HADDR(0, row, g0)]) = make_uint4(0, 0, 0, 0);
    }
    __syncthreads();

    // ================= layer 2: h2 = relu(h1 @ W2 + b2) =================
    v4f acc2[2][7];
    #pragma unroll
    for (int mt = 0; mt < 2; ++mt)
        #pragma unroll
        for (int nt = 0; nt < 7; ++nt) acc2[mt][nt] = (v4f){0.f, 0.f, 0.f, 0.f};
    float bv2[7];
    #pragma unroll
    for (int nt = 0; nt < 7; ++nt) {
        const int c = nt * 16 + l15;
        bv2[nt] = (c < 100) ? b2[c] : 0.f;
    }
    #pragma unroll
    for (int kc = 0; kc < 4; ++kc) {
        v8s af[2];
        #pragma unroll
        for (int mt = 0; mt < 2; ++mt) {
            const int row = wid * 32 + mt * 16 + l15;
            uint4 t = *(const uint4*)(&L[HADDR(0, row, kc * 4 + l4)]);
            af[mt] = *(v8s*)&t;
        }
        #pragma unroll
        for (int nt = 0; nt < 7; ++nt) {
            uint4 bu = wf[W2F_U4 + (nt * 4 + kc) * 64 + lane];
            v8s bf = *(v8s*)&bu;
            acc2[0][nt] = mfma16(af[0], bf, acc2[0][nt]);
            acc2[1][nt] = mfma16(af[1], bf, acc2[1][nt]);
        }
    }
    // epilogue -> h2 (region B; X is dead, all waves past the chunk barriers)
    #pragma unroll
    for (int mt = 0; mt < 2; ++mt)
        #pragma unroll
        for (int nt = 0; nt < 7; ++nt) {
            v4f a = acc2[mt][nt];
            #pragma unroll
            for (int r = 0; r < 4; ++r) {
                const int row = wid * 32 + mt * 16 + l4 * 4 + r;
                const int c   = nt * 16 + l15;
                const float v = fmaxf(a[r] + bv2[nt], 0.f);
                *(unsigned short*)(&L[HADDR(HB, row, c >> 3) + (c & 7) * 2]) = f2bf(v);
            }
        }
    {
        const int row = tid >> 1, g0 = 14 + (tid & 1);
        *(uint4*)(&L[HADDR(HB, row, g0)]) = make_uint4(0, 0, 0, 0);
    }
    __syncthreads();   // fences h1 reads (region A free) + h2 writes visible

    // ================= layer 3: DP = h2 @ W3 + b3 =================
    v4f acc3[2][4];
    #pragma unroll
    for (int mt = 0; mt < 2; ++mt)
        #pragma unroll
        for (int nt = 0; nt < 4; ++nt) acc3[mt][nt] = (v4f){0.f, 0.f, 0.f, 0.f};
    float bv3[4];
    #pragma unroll
    for (int nt = 0; nt < 4; ++nt) bv3[nt] = b3[nt * 16 + l15];

    #pragma unroll
    for (int kc = 0; kc < 4; ++kc) {
        v8s af[2];
        #pragma unroll
        for (int mt = 0; mt < 2; ++mt) {
            const int row = wid * 32 + mt * 16 + l15;
            uint4 t = *(const uint4*)(&L[HADDR(HB, row, kc * 4 + l4)]);
            af[mt] = *(v8s*)&t;
        }
        #pragma unroll
        for (int nt = 0; nt < 4; ++nt) {
            uint4 bu = wf[W3F_U4 + (nt * 4 + kc) * 64 + lane];
            v8s bf = *(v8s*)&bu;
            acc3[0][nt] = mfma16(af[0], bf, acc3[0][nt]);
            acc3[1][nt] = mfma16(af[1], bf, acc3[1][nt]);
        }
    }
    // DP (f32) -> region A; safe: all h1 reads ended at the previous barrier
    #pragma unroll
    for (int mt = 0; mt < 2; ++mt)
        #pragma unroll
        for (int nt = 0; nt < 4; ++nt) {
            v4f a = acc3[mt][nt];
            #pragma unroll
            for (int r = 0; r < 4; ++r) {
                const int row = wid * 32 + mt * 16 + l4 * 4 + r;
                const int c   = nt * 16 + l15;
                *(float*)(&L[DPADDR(row, c >> 2) + (c & 3) * 4]) = a[r] + bv3[nt];
            }
        }
    __syncthreads();

    // ================= Student-t GAS recurrence (thread-per-row) =========
    if (tid < BMROWS) {
        const size_t rg = rowg0 + tid;
        float mu = last_mu[rg];
        float s2 = last_sigma[rg];
        const float anu = *p_nu,  ans = *p_ns;
        const float aMu = *p_amu, aSg = *p_as;
        const float bMu = *p_bmu, bSg = *p_bs;
        const float oMu = *p_omu, oSg = *p_os;
        const float w   = 1.f + __builtin_amdgcn_rcpf(anu);
        const float cmu = ans * aMu * w;
        const float cs  = ans * aSg * w;
        const float bs2 = bSg - ans * aSg;

#define GAS_STEP(Y, O)                                                  \
        {   const float e    = (Y) - mu;                                \
            const float nus2 = anu * s2;                                \
            const float den  = fmaf(e, e, nus2);                        \
            const float r0   = __builtin_amdgcn_rcpf(den);              \
            const float p    = e * nus2 * r0;                           \
            mu = fmaf(cmu, p, fmaf(bMu, mu, oMu));                      \
            s2 = fmaf(cs, e * p, fmaf(bs2, s2, oSg));                   \
            (O) = fmaf((Y), __builtin_amdgcn_sqrtf(s2), mu); }

        #pragma unroll
        for (int q = 0; q < 16; ++q) {
            float4 d = *(float4*)(&L[DPADDR(tid, q)]);
            float o0, o1, o2, o3;
            GAS_STEP(d.x, o0); GAS_STEP(d.y, o1);
            GAS_STEP(d.z, o2); GAS_STEP(d.w, o3);
            *(float4*)(&L[DPADDR(tid, q)]) = make_float4(o0, o1, o2, o3);
        }
#undef GAS_STEP
    }
    __syncthreads();

    // ================= coalesced float4 store =================
    #pragma unroll
    for (int i = 0; i < 8; ++i) {
        const int fi  = i * THREADS + tid;
        const int row = fi >> 4, q = fi & 15;
        float4 v = *(float4*)(&L[DPADDR(row, q)]);
        ((float4*)out)[(size_t)blk * 2048 + fi] = v;
    }
}

extern "C" void kernel_launch(void* const* d_in, const int* in_sizes, int n_in,
                              void* d_out, int out_size, void* d_ws, size_t ws_size,
                              hipStream_t stream) {
    const float* x          = (const float*)d_in[0];
    const float* last_mu    = (const float*)d_in[1];
    const float* last_sigma = (const float*)d_in[2];
    const float* amu        = (const float*)d_in[3];
    const float* asig       = (const float*)d_in[4];
    const float* bmu        = (const float*)d_in[5];
    const float* bsig       = (const float*)d_in[6];
    const float* omu        = (const float*)d_in[7];
    const float* osig       = (const float*)d_in[8];
    const float* nu         = (const float*)d_in[9];
    const float* ns         = (const float*)d_in[10];
    const float* W1         = (const float*)d_in[11];
    const float* b1         = (const float*)d_in[12];
    const float* W2         = (const float*)d_in[13];
    const float* b2         = (const float*)d_in[14];
    const float* W3         = (const float*)d_in[15];
    const float* b3         = (const float*)d_in[16];
    float* out = (float*)d_out;

    uint4* wf = (uint4*)d_ws;   // 95,232 B of fragment-ready bf16 weights
    prep_weights<<<93, 64, 0, stream>>>(W1, W2, W3, wf);

    const int B = in_sizes[1];                 // 262144
    dim3 grid(B / BMROWS), block(THREADS);
    ar_gas_mfma<<<grid, block, 0, stream>>>(
        x, last_mu, last_sigma,
        amu, asig, bmu, bsig, omu, osig, nu, ns,
        b1, b2, b3, wf, out);
}